// Round 4
// baseline (948.178 us; speedup 1.0000x reference)
//
#include <hip/hip_runtime.h>

#define MM 1024
#define NN 4096
#define DD 128
#define HH 32
#define PP 3072
#define LL 4096   // P + M

typedef __attribute__((ext_vector_type(8))) short short8;
typedef __attribute__((ext_vector_type(4))) float f32x4;

__device__ __forceinline__ float bf2f(short b) {
  union { unsigned u; float f; } c;
  c.u = ((unsigned)(unsigned short)b) << 16;
  return c.f;
}

__device__ __forceinline__ short f2bf(float f) {
  union { float f; unsigned u; } c; c.f = f;
  unsigned r = c.u + 0x7FFFu + ((c.u >> 16) & 1u);  // RNE
  return (short)(r >> 16);
}

// split f32 -> bf16 hi + bf16 lo (x ~= hi + lo, residual ~2^-16 rel)
struct bf2 { short hi, lo; };
__device__ __forceinline__ bf2 split2(float x) {
  bf2 r;
  r.hi = f2bf(x);
  r.lo = f2bf(x - bf2f(r.hi));
  return r;
}

// 8 consecutive f32 -> 8 bf16 (plain cast)
__device__ __forceinline__ short8 cvt8(const float* __restrict__ p) {
  const f32x4 a = *(const f32x4*)p;
  const f32x4 b = *(const f32x4*)(p + 4);
  short8 r;
  r[0] = f2bf(a[0]); r[1] = f2bf(a[1]); r[2] = f2bf(a[2]); r[3] = f2bf(a[3]);
  r[4] = f2bf(b[0]); r[5] = f2bf(b[1]); r[6] = f2bf(b[2]); r[7] = f2bf(b[3]);
  return r;
}

// async global -> LDS, 16B per lane, LDS dest = wave-uniform base + lane*16
__device__ __forceinline__ void gload16(const void* g, void* l) {
  __builtin_amdgcn_global_load_lds(
      (const __attribute__((address_space(1))) void*)g,
      (__attribute__((address_space(3))) void*)l, 16, 0, 0);
}

// ---------------------------------------------------------------------------
// Split X f32 -> Xhi, Xlo bf16 (8 elems/thread).
// ---------------------------------------------------------------------------
__global__ __launch_bounds__(256) void split_x(
    const float* __restrict__ in, short* __restrict__ oh,
    short* __restrict__ ol, int n8)
{
  int i = blockIdx.x * blockDim.x + threadIdx.x;
  if (i >= n8) return;
  const float* p = in + (size_t)i * 8;
  f32x4 a = *(const f32x4*)p, b = *(const f32x4*)(p + 4);
  short8 h, l;
  #pragma unroll
  for (int j = 0; j < 4; ++j) {
    bf2 ra = split2(a[j]); h[j] = ra.hi; l[j] = ra.lo;
    bf2 rb = split2(b[j]); h[4 + j] = rb.hi; l[4 + j] = rb.lo;
  }
  *(short8*)(oh + (size_t)i * 8) = h;
  *(short8*)(ol + (size_t)i * 8) = l;
}

// ---------------------------------------------------------------------------
// Split + transpose W: f32 [K][N] -> bf16 hi/lo [N][K] (K-major).
// ---------------------------------------------------------------------------
__global__ __launch_bounds__(256) void split_w_t(
    const float* __restrict__ W, short* __restrict__ oh,
    short* __restrict__ ol)
{
  const int n0 = blockIdx.x * 256;
  const int k0 = blockIdx.y * 64;
  const int t  = threadIdx.x;
  const int k8 = k0 + ((t >> 5) << 3);   // 8-row k block
  const int n8 = n0 + ((t & 31) << 3);   // 8-col n block

  f32x4 xa[8], xb[8];
  #pragma unroll
  for (int r = 0; r < 8; ++r) {
    const float* p = W + (size_t)(k8 + r) * 4096 + n8;
    xa[r] = *(const f32x4*)p;
    xb[r] = *(const f32x4*)(p + 4);
  }
  #pragma unroll
  for (int c = 0; c < 8; ++c) {
    short8 th, tl;
    #pragma unroll
    for (int r = 0; r < 8; ++r) {
      float v = (c < 4) ? xa[r][c] : xb[r][c - 4];
      bf2 s = split2(v);
      th[r] = s.hi; tl[r] = s.lo;
    }
    size_t o = (size_t)(n8 + c) * 4096 + k8;
    *(short8*)(oh + o) = th;
    if (ol) *(short8*)(ol + o) = tl;
  }
}

// ---------------------------------------------------------------------------
// Split-precision bf16 GEMM, B^T layout (m97 structure):
//   O f32 [M][N] = Xh+Xl  @  (Wh+Wl)^T   (3 MFMA terms: hh, hl, lh)
// ---------------------------------------------------------------------------
__global__ __launch_bounds__(256) void gemm_split_bt(
    const short* __restrict__ Ah_g, const short* __restrict__ Al_g,
    const short* __restrict__ Bh_g, const short* __restrict__ Bl_g,
    float* __restrict__ O)
{
  const int n0 = blockIdx.x * 128;
  const int m0 = blockIdx.y * 128;
  const int t  = threadIdx.x;
  const int wave = t >> 6;
  const int lane = t & 63;
  const int ln   = lane & 15;
  const int quad = lane >> 4;
  const int q8   = quad * 8;
  const int wm = (wave >> 1) * 64;
  const int wn = (wave & 1) * 64;
  const int sr = lane >> 3;        // sub-row within 8-row staging chunk
  const int sc = (lane & 7) * 8;   // k offset within row

  __shared__ short Ash[128 * 64];
  __shared__ short Asl[128 * 64];
  __shared__ short Bsh[128 * 64];
  __shared__ short Bsl[128 * 64];

  f32x4 acc[4][4];
  #pragma unroll
  for (int mi = 0; mi < 4; ++mi)
    #pragma unroll
    for (int ni = 0; ni < 4; ++ni)
      acc[mi][ni] = (f32x4){0.f, 0.f, 0.f, 0.f};

  const size_t a_base = (size_t)(m0 + wave * 32 + sr) * 4096 + sc;
  const size_t b_base = (size_t)(n0 + wave * 32 + sr) * 4096 + sc;
  const int l_base = wave * 32 * 64;  // shorts

  for (int kt = 0; kt < 4096; kt += 64) {
    #pragma unroll
    for (int i = 0; i < 4; ++i) {
      size_t ao = a_base + kt + (size_t)(i * 8) * 4096;
      size_t bo = b_base + kt + (size_t)(i * 8) * 4096;
      int lo = l_base + i * 8 * 64;
      gload16(Ah_g + ao, Ash + lo);
      gload16(Al_g + ao, Asl + lo);
      gload16(Bh_g + bo, Bsh + lo);
      gload16(Bl_g + bo, Bsl + lo);
    }
    __syncthreads();
    #pragma unroll
    for (int kk = 0; kk < 64; kk += 32) {
      short8 ah[4], al[4], bh[4], bl[4];
      #pragma unroll
      for (int mi = 0; mi < 4; ++mi) {
        int ro = (wm + mi * 16 + ln) * 64 + kk + q8;
        ah[mi] = *(const short8*)(Ash + ro);
        al[mi] = *(const short8*)(Asl + ro);
      }
      #pragma unroll
      for (int ni = 0; ni < 4; ++ni) {
        int ro = (wn + ni * 16 + ln) * 64 + kk + q8;
        bh[ni] = *(const short8*)(Bsh + ro);
        bl[ni] = *(const short8*)(Bsl + ro);
      }
      #pragma unroll
      for (int ni = 0; ni < 4; ++ni)
        #pragma unroll
        for (int mi = 0; mi < 4; ++mi) {
          acc[mi][ni] = __builtin_amdgcn_mfma_f32_16x16x32_bf16(ah[mi], bh[ni], acc[mi][ni], 0, 0, 0);
          acc[mi][ni] = __builtin_amdgcn_mfma_f32_16x16x32_bf16(ah[mi], bl[ni], acc[mi][ni], 0, 0, 0);
          acc[mi][ni] = __builtin_amdgcn_mfma_f32_16x16x32_bf16(al[mi], bh[ni], acc[mi][ni], 0, 0, 0);
        }
    }
    __syncthreads();
  }

  #pragma unroll
  for (int mi = 0; mi < 4; ++mi)
    #pragma unroll
    for (int ni = 0; ni < 4; ++ni)
      #pragma unroll
      for (int r = 0; r < 4; ++r) {
        int row = m0 + wm + mi * 16 + quad * 4 + r;
        int col = n0 + wn + ni * 16 + ln;
        O[(size_t)row * 4096 + col] = acc[mi][ni][r];
      }
}

// ---------------------------------------------------------------------------
// Plain bf16 GEMM, B^T layout: Ov bf16 = Xh @ Wth^T.
// ---------------------------------------------------------------------------
__global__ __launch_bounds__(256) void gemm_bf16_bt(
    const short* __restrict__ Ah_g, const short* __restrict__ Bh_g,
    short* __restrict__ Ov)
{
  const int n0 = blockIdx.x * 128;
  const int m0 = blockIdx.y * 128;
  const int t  = threadIdx.x;
  const int wave = t >> 6;
  const int lane = t & 63;
  const int ln   = lane & 15;
  const int quad = lane >> 4;
  const int q8   = quad * 8;
  const int wm = (wave >> 1) * 64;
  const int wn = (wave & 1) * 64;
  const int sr = lane >> 3;
  const int sc = (lane & 7) * 8;

  __shared__ short Ash[128 * 64];
  __shared__ short Bsh[128 * 64];

  f32x4 acc[4][4];
  #pragma unroll
  for (int mi = 0; mi < 4; ++mi)
    #pragma unroll
    for (int ni = 0; ni < 4; ++ni)
      acc[mi][ni] = (f32x4){0.f, 0.f, 0.f, 0.f};

  const size_t a_base = (size_t)(m0 + wave * 32 + sr) * 4096 + sc;
  const size_t b_base = (size_t)(n0 + wave * 32 + sr) * 4096 + sc;
  const int l_base = wave * 32 * 64;

  for (int kt = 0; kt < 4096; kt += 64) {
    #pragma unroll
    for (int i = 0; i < 4; ++i) {
      size_t ao = a_base + kt + (size_t)(i * 8) * 4096;
      size_t bo = b_base + kt + (size_t)(i * 8) * 4096;
      int lo = l_base + i * 8 * 64;
      gload16(Ah_g + ao, Ash + lo);
      gload16(Bh_g + bo, Bsh + lo);
    }
    __syncthreads();
    #pragma unroll
    for (int kk = 0; kk < 64; kk += 32) {
      short8 ah[4], bh[4];
      #pragma unroll
      for (int mi = 0; mi < 4; ++mi)
        ah[mi] = *(const short8*)(Ash + (wm + mi * 16 + ln) * 64 + kk + q8);
      #pragma unroll
      for (int ni = 0; ni < 4; ++ni)
        bh[ni] = *(const short8*)(Bsh + (wn + ni * 16 + ln) * 64 + kk + q8);
      #pragma unroll
      for (int ni = 0; ni < 4; ++ni)
        #pragma unroll
        for (int mi = 0; mi < 4; ++mi)
          acc[mi][ni] = __builtin_amdgcn_mfma_f32_16x16x32_bf16(ah[mi], bh[ni], acc[mi][ni], 0, 0, 0);
    }
    __syncthreads();
  }

  #pragma unroll
  for (int mi = 0; mi < 4; ++mi)
    #pragma unroll
    for (int ni = 0; ni < 4; ++ni)
      #pragma unroll
      for (int r = 0; r < 4; ++r) {
        int row = m0 + wm + mi * 16 + quad * 4 + r;
        int col = n0 + wn + ni * 16 + ln;
        Ov[(size_t)row * 4096 + col] = f2bf(acc[mi][ni][r]);
      }
}

// ---------------------------------------------------------------------------
// prep_k: cK (f32) + Kf (f32 raw GEMM output) -> Khi/Klo bf16 [H][4096][128].
// RMS-norm fused for the new keys (key >= PP): 8 lanes share a row.
// 16B-block XOR swizzle baked in: logical d-block b stored at b ^ (key&7).
// ---------------------------------------------------------------------------
__global__ __launch_bounds__(256) void prep_k(
    const float* __restrict__ Kf, const float* __restrict__ cK,
    short* __restrict__ Khi, short* __restrict__ Klo)
{
  const int h  = blockIdx.y;
  const int k0 = blockIdx.x * 64;
  const int t  = threadIdx.x;
  const int d0 = (t & 7) * 16;   // 16 f32 per thread per row
  #pragma unroll
  for (int i = 0; i < 2; ++i) {
    int key = k0 + i * 32 + (t >> 3);
    const bool isnew = (key >= PP);   // uniform per block (PP % 64 == 0)
    const float* src = !isnew
        ? cK + ((size_t)h * PP + key) * 128 + d0
        : Kf + (size_t)(key - PP) * 4096 + h * 128 + d0;
    f32x4 x0 = *(const f32x4*)src,       x1 = *(const f32x4*)(src + 4);
    f32x4 x2 = *(const f32x4*)(src + 8), x3 = *(const f32x4*)(src + 12);
    if (isnew) {
      float ss = 0.f;
      #pragma unroll
      for (int j = 0; j < 4; ++j)
        ss += x0[j]*x0[j] + x1[j]*x1[j] + x2[j]*x2[j] + x3[j]*x3[j];
      ss += __shfl_xor(ss, 1, 64);
      ss += __shfl_xor(ss, 2, 64);
      ss += __shfl_xor(ss, 4, 64);
      float sc = rsqrtf(ss * (1.0f / 128.0f));
      #pragma unroll
      for (int j = 0; j < 4; ++j) {
        x0[j] *= sc; x1[j] *= sc; x2[j] *= sc; x3[j] *= sc;
      }
    }
    short8 h0, l0, h1, l1;
    #pragma unroll
    for (int j = 0; j < 4; ++j) {
      bf2 r0 = split2(x0[j]); h0[j] = r0.hi; l0[j] = r0.lo;
      bf2 r1 = split2(x1[j]); h0[4 + j] = r1.hi; l0[4 + j] = r1.lo;
      bf2 r2 = split2(x2[j]); h1[j] = r2.hi; l1[j] = r2.lo;
      bf2 r3 = split2(x3[j]); h1[4 + j] = r3.hi; l1[4 + j] = r3.lo;
    }
    size_t row = ((size_t)h * 4096 + key) * 128;
    int s  = key & 7;
    int b0 = (t & 7) * 2, b1 = b0 + 1;
    *(short8*)(Khi + row + ((b0 ^ s) << 3)) = h0;
    *(short8*)(Khi + row + ((b1 ^ s) << 3)) = h1;
    *(short8*)(Klo + row + ((b0 ^ s) << 3)) = l0;
    *(short8*)(Klo + row + ((b1 ^ s) << 3)) = l1;
  }
}

// ---------------------------------------------------------------------------
// prep_v: cV (f32) + Vb (bf16) -> Vtt bf16, pre-transposed + pre-tiled:
// [H][tile=L/64][d=128][key=64], swizzled (key-block kb stored at kb^(d&7)).
// ---------------------------------------------------------------------------
__global__ __launch_bounds__(256) void prep_v(
    const short* __restrict__ Vb, const float* __restrict__ cV,
    short* __restrict__ Vtt)
{
  const int h    = blockIdx.y;
  const int k0   = blockIdx.x * 128;
  const int t    = threadIdx.x;
  const int kb_g = (k0 >> 3) + (t >> 4);  // global key-8-block
  const int db   = t & 15;                // d-8-block
  const int key0 = kb_g * 8;

  short8 row[8];
  if (key0 < PP) {
    #pragma unroll
    for (int r = 0; r < 8; ++r)
      row[r] = cvt8(cV + ((size_t)h * PP + key0 + r) * 128 + db * 8);
  } else {
    #pragma unroll
    for (int r = 0; r < 8; ++r)
      row[r] = *(const short8*)(Vb + (size_t)(key0 + r - PP) * 4096 + h * 128 + db * 8);
  }

  const int tile = kb_g >> 3, kbt = kb_g & 7;
  size_t tb = ((size_t)h * 64 + tile) * 8192;
  #pragma unroll
  for (int c = 0; c < 8; ++c) {
    int d = db * 8 + c;                  // d & 7 == c
    short8 o;
    #pragma unroll
    for (int r = 0; r < 8; ++r) o[r] = row[r][c];
    *(short8*)(Vtt + tb + d * 64 + ((kbt ^ c) << 3)) = o;
  }
}

// ---------------------------------------------------------------------------
// Flash attention, 128 q-rows/block, 4 waves, grid (8, 32) = 1 block/CU.
// Wave w owns q-rows [w*32, w*32+32) for BOTH QK/softmax AND PV, so P (p_s)
// never crosses waves: the p_s round-trip is wave-local (no barrier), alpha
// and l stay in registers, and the only block-wide sync is one
// __syncthreads() per K/V-tile. K/V double-buffered in LDS: next tile's
// global_load_lds issued before compute, drained by the end-of-iteration
// __syncthreads (safe 2-phase pattern, no raw barriers / manual waitcnt).
// Q rms-norm fused into the Q-load.
// ---------------------------------------------------------------------------
__global__ __launch_bounds__(256, 1) void attn(
    const float* __restrict__ Qf,   // [M][4096] f32 raw q (norm fused here)
    const short* __restrict__ Khi,  // [H][L][128] bf16 swizzled, normed
    const short* __restrict__ Klo,
    const short* __restrict__ Vtt,  // [H][L/64][128][64] bf16 swizzled
    float* __restrict__ Out)        // [M][4096] f32
{
  const int h  = blockIdx.y;
  const int m0 = blockIdx.x * 128;
  const int t  = threadIdx.x;
  const int w    = t >> 6;
  const int lane = t & 63;
  const int ln   = lane & 15;
  const int quad = lane >> 4;
  const int q8   = quad * 8;

  __shared__ short k_hi[2 * 64 * 128];
  __shared__ short k_lo[2 * 64 * 128];
  __shared__ short v_t[2 * 128 * 64];
  __shared__ short p_s[128 * 72];

  // q fragments: load 32 f32/lane, fused rms-norm (sum over 4 quads), split
  short8 qh[2][4], ql[2][4];
  #pragma unroll
  for (int mi = 0; mi < 2; ++mi) {
    int qrow = m0 + w * 32 + mi * 16 + ln;
    f32x4 xa[4], xb[4];
    float ss = 0.f;
    #pragma unroll
    for (int dc = 0; dc < 4; ++dc) {
      const float* qp = Qf + (size_t)qrow * 4096 + h * 128 + dc * 32 + q8;
      xa[dc] = *(const f32x4*)qp;
      xb[dc] = *(const f32x4*)(qp + 4);
      #pragma unroll
      for (int j = 0; j < 4; ++j)
        ss += xa[dc][j] * xa[dc][j] + xb[dc][j] * xb[dc][j];
    }
    ss += __shfl_xor(ss, 16, 64);
    ss += __shfl_xor(ss, 32, 64);
    float scale = rsqrtf(ss * (1.0f / 128.0f));
    #pragma unroll
    for (int dc = 0; dc < 4; ++dc) {
      #pragma unroll
      for (int j = 0; j < 4; ++j) {
        bf2 ra = split2(xa[dc][j] * scale);
        qh[mi][dc][j] = ra.hi; ql[mi][dc][j] = ra.lo;
        bf2 rb = split2(xb[dc][j] * scale);
        qh[mi][dc][4 + j] = rb.hi; ql[mi][dc][4 + j] = rb.lo;
      }
    }
  }

  float m_st[2][4], l_st[2][4];
  #pragma unroll
  for (int mi = 0; mi < 2; ++mi)
    #pragma unroll
    for (int r = 0; r < 4; ++r) { m_st[mi][r] = -1e30f; l_st[mi][r] = 0.f; }

  f32x4 oacc[2][8];   // [row-subtile][d-subtile] for the wave's own 32 rows
  #pragma unroll
  for (int mi = 0; mi < 2; ++mi)
    #pragma unroll
    for (int ds = 0; ds < 8; ++ds)
      oacc[mi][ds] = (f32x4){0.f, 0.f, 0.f, 0.f};

  const size_t khead = (size_t)h * 4096 * 128;
  const size_t vhead = (size_t)h * 64 * 8192;

  // prologue: stage tile 0 into buffer 0, full drain once
  #pragma unroll
  for (int i = 0; i < 4; ++i) {
    int lo = i * 2048 + w * 512;
    gload16(Khi + khead + lo + lane * 8, k_hi + lo);
    gload16(Klo + khead + lo + lane * 8, k_lo + lo);
    gload16(Vtt + vhead + lo + lane * 8, v_t + lo);
  }
  __syncthreads();

  for (int it = 0; it < 64; ++it) {
    const int cur = it & 1;
    const short* khb = k_hi + cur * 8192;
    const short* klb = k_lo + cur * 8192;
    const short* vtb = v_t  + cur * 8192;

    // issue next tile's staging into the other buffer; it flies during
    // this tile's compute and is drained by the end-of-iteration barrier
    if (it < 63) {
      const size_t kt = khead + (size_t)(it + 1) * 8192;
      const size_t vt = vhead + (size_t)(it + 1) * 8192;
      const int bb = (1 - cur) * 8192;
      #pragma unroll
      for (int i = 0; i < 4; ++i) {
        int lo = i * 2048 + w * 512;
        gload16(Khi + kt + lo + lane * 8, k_hi + bb + lo);
        gload16(Klo + kt + lo + lane * 8, k_lo + bb + lo);
        gload16(Vtt + vt + lo + lane * 8, v_t + bb + lo);
      }
    }

    // ---- S = q K^T: each K fragment pair feeds 6 MFMAs (2 mi x 3 terms)
    f32x4 sacc[2][4];
    #pragma unroll
    for (int mi = 0; mi < 2; ++mi)
      #pragma unroll
      for (int ni = 0; ni < 4; ++ni)
        sacc[mi][ni] = (f32x4){0.f, 0.f, 0.f, 0.f};
    __builtin_amdgcn_s_setprio(1);
    #pragma unroll
    for (int ni = 0; ni < 4; ++ni) {
      const int r = ni * 16 + ln;
      #pragma unroll
      for (int dc = 0; dc < 4; ++dc) {
        int ro = r * 128 + (((dc * 4 + quad) ^ (r & 7)) << 3);
        short8 kh = *(const short8*)(khb + ro);
        short8 kl = *(const short8*)(klb + ro);
        #pragma unroll
        for (int mi = 0; mi < 2; ++mi) {
          sacc[mi][ni] = __builtin_amdgcn_mfma_f32_16x16x32_bf16(qh[mi][dc], kh, sacc[mi][ni], 0, 0, 0);
          sacc[mi][ni] = __builtin_amdgcn_mfma_f32_16x16x32_bf16(qh[mi][dc], kl, sacc[mi][ni], 0, 0, 0);
          sacc[mi][ni] = __builtin_amdgcn_mfma_f32_16x16x32_bf16(ql[mi][dc], kh, sacc[mi][ni], 0, 0, 0);
        }
      }
    }
    __builtin_amdgcn_s_setprio(0);

    // ---- wave-private online softmax; alpha stays in registers
    float alpha[2][4];
    #pragma unroll
    for (int mi = 0; mi < 2; ++mi) {
      #pragma unroll
      for (int rr = 0; rr < 4; ++rr) {
        float mx = fmaxf(fmaxf(sacc[mi][0][rr], sacc[mi][1][rr]),
                         fmaxf(sacc[mi][2][rr], sacc[mi][3][rr]));
        #pragma unroll
        for (int d = 1; d < 16; d <<= 1) mx = fmaxf(mx, __shfl_xor(mx, d, 64));
        float mn = fmaxf(m_st[mi][rr], mx);
        alpha[mi][rr] = __expf(m_st[mi][rr] - mn);
        float p0 = __expf(sacc[mi][0][rr] - mn);
        float p1 = __expf(sacc[mi][1][rr] - mn);
        float p2 = __expf(sacc[mi][2][rr] - mn);
        float p3 = __expf(sacc[mi][3][rr] - mn);
        float s = p0 + p1 + p2 + p3;
        #pragma unroll
        for (int d = 1; d < 16; d <<= 1) s += __shfl_xor(s, d, 64);
        l_st[mi][rr] = l_st[mi][rr] * alpha[mi][rr] + s;
        m_st[mi][rr] = mn;
        int prow = (w * 32 + mi * 16 + quad * 4 + rr) * 72;
        p_s[prow + 0 * 16 + ln] = f2bf(p0);
        p_s[prow + 1 * 16 + ln] = f2bf(p1);
        p_s[prow + 2 * 16 + ln] = f2bf(p2);
        p_s[prow + 3 * 16 + ln] = f2bf(p3);
      }
    }

    // ---- rescale O (registers only; rows match lane's quad)
    #pragma unroll
    for (int mi = 0; mi < 2; ++mi)
      #pragma unroll
      for (int ds = 0; ds < 8; ++ds)
        #pragma unroll
        for (int r = 0; r < 4; ++r)
          oacc[mi][ds][r] *= alpha[mi][r];

    // ---- O += P V for the wave's own 32 rows x all 128 d (p_s wave-local;
    //      compiler inserts the lgkmcnt wait for the p_s write->read dep)
    #pragma unroll
    for (int kk = 0; kk < 64; kk += 32) {
      short8 vf[8];
      #pragma unroll
      for (int ds = 0; ds < 8; ++ds) {
        int d = ds * 16 + ln;
        int ro = d * 64 + ((((kk + q8) >> 3) ^ (d & 7)) << 3);
        vf[ds] = *(const short8*)(vtb + ro);
      }
      __builtin_amdgcn_s_setprio(1);
      #pragma unroll
      for (int mi = 0; mi < 2; ++mi) {
        short8 pf = *(const short8*)(p_s + (w * 32 + mi * 16 + ln) * 72 + kk + q8);
        #pragma unroll
        for (int ds = 0; ds < 8; ++ds)
          oacc[mi][ds] = __builtin_amdgcn_mfma_f32_16x16x32_bf16(pf, vf[ds], oacc[mi][ds], 0, 0, 0);
      }
      __builtin_amdgcn_s_setprio(0);
    }

    // one barrier per tile: protects LDS buffer reuse and drains the
    // in-flight prefetch (vmcnt/lgkmcnt 0 implied by __syncthreads)
    __syncthreads();
  }

  // epilogue: l_st is in registers, rows match lane's quad
  #pragma unroll
  for (int mi = 0; mi < 2; ++mi) {
    #pragma unroll
    for (int ds = 0; ds < 8; ++ds) {
      int col = h * 128 + ds * 16 + ln;
      #pragma unroll
      for (int r = 0; r < 4; ++r) {
        int row = m0 + w * 32 + mi * 16 + quad * 4 + r;
        Out[(size_t)row * 4096 + col] = oacc[mi][ds][r] / l_st[mi][r];
      }
    }
  }
}

// ---------------------------------------------------------------------------
extern "C" void kernel_launch(void* const* d_in, const int* in_sizes, int n_in,
                              void* d_out, int out_size, void* d_ws, size_t ws_size,
                              hipStream_t stream) {
  const float* X  = (const float*)d_in[0];
  const float* Wq = (const float*)d_in[1];
  const float* Wk = (const float*)d_in[2];
  const float* Wv = (const float*)d_in[3];
  const float* cK = (const float*)d_in[4];
  const float* cV = (const float*)d_in[5];
  float* out = (float*)d_out;

  const size_t MB = 1u << 20;
  char* w = (char*)d_ws;
  // Phase-1 layout (projections):
  float* Qf  = (float*)(w);             // 16 MB [0,16)
  float* Kf  = (float*)(w + 16 * MB);   // 16 MB [16,32)
  short* Xh  = (short*)(w + 32 * MB);   //  8 MB [32,40)
  short* Xl  = (short*)(w + 40 * MB);   //  8 MB [40,48)
  short* Vb  = (short*)(w + 48 * MB);   //  8 MB [48,56)
  short* Wth = (short*)(w + 56 * MB);   // 32 MB [56,88)
  short* Wtl = (short*)(w + 88 * MB);   // 32 MB [88,120)
  // Phase-2 overlays (after producers are done on the same stream):
  short* Khi = (short*)(w + 56 * MB);   // 32 MB over Wth (dead after gemms)
  short* Klo = (short*)(w + 88 * MB);   // 32 MB over Wtl (dead after gemms)
  short* Vtt = (short*)(w + 16 * MB);   // 32 MB over Kf/Xh/Xl (dead after prep_k)

  {
    int n8 = (int)((size_t)MM * NN / 8);
    split_x<<<n8 / 256, 256, 0, stream>>>(X, Xh, Xl, n8);
  }

  dim3 gw(NN / 256, NN / 64);
  dim3 gg(NN / 128, MM / 128);

  // Q projection
  split_w_t<<<gw, 256, 0, stream>>>(Wq, Wth, Wtl);
  gemm_split_bt<<<gg, 256, 0, stream>>>(Xh, Xl, Wth, Wtl, Qf);

  // K projection (reuse transposed-weight buffers)
  split_w_t<<<gw, 256, 0, stream>>>(Wk, Wth, Wtl);
  gemm_split_bt<<<gg, 256, 0, stream>>>(Xh, Xl, Wth, Wtl, Kf);

  // V projection (hi only)
  split_w_t<<<gw, 256, 0, stream>>>(Wv, Wth, nullptr);
  gemm_bf16_bt<<<gg, 256, 0, stream>>>(Xh, Wth, Vb);

  // K/V pre-split/transpose for attention (rms-norm fused into prep_k for K
  // and into attn's Q-load for Q). Order matters: prep_k reads Kf, prep_v's
  // output overlays Kf.
  dim3 gk(LL / 64, HH);
  prep_k<<<gk, 256, 0, stream>>>(Kf, cK, Khi, Klo);
  dim3 gv(LL / 128, HH);
  prep_v<<<gv, 256, 0, stream>>>(Vb, cV, Vtt);

  dim3 ga(MM / 128, HH);
  attn<<<ga, 256, 0, stream>>>(Qf, Khi, Klo, Vtt, out);
}